// Round 1
// baseline (1139.677 us; speedup 1.0000x reference)
//
#include <hip/hip_runtime.h>
#include <math.h>

// VectorQuantizer: B=32, K=4096, D=64, C=1024.
// out layout (fp32 flat): z_q_st [8388608] | total_loss [1] | indices-as-float [131072]
// ws layout (floats): wt[64*1024] | wsq[1024] | probpart[64*1024] | distsum[1]

#define NROWS 131072
#define DDIM  64
#define CSZ   1024
#define TR    16      // rows per block; s-tile = 16*1024*4B = 64 KB LDS exactly
#define NSLOT 64      // prob partial copies (atomic contention spreading)

__device__ __forceinline__ void top2_insert(float v, int c,
                                            float& m1, int& i1, float& m2, int& i2) {
  const bool lt1 = (v < m1) || (v == m1 && c < i1);
  const bool lt2 = (v < m2) || (v == m2 && c < i2);
  if (lt1) { m2 = m1; i2 = i1; m1 = v; i1 = c; }
  else if (lt2) { m2 = v; i2 = c; }
}

// ---- prep: transpose codebook to wt[d][c], codebook norms, zero accumulators ----
__global__ __launch_bounds__(256) void vq_prep(const float* __restrict__ cb,
                                               float* __restrict__ wt,
                                               float* __restrict__ wsq,
                                               float* __restrict__ probpart,
                                               float* __restrict__ distsum) {
  const int t = blockIdx.x * 256 + threadIdx.x;   // grid = 64 blocks -> 16384 threads
  for (int i = t; i < NSLOT * CSZ; i += 16384) probpart[i] = 0.0f;
  if (t == 0) distsum[0] = 0.0f;
  for (int i = t; i < CSZ * DDIM; i += 16384) {
    const int c = i >> 6, d = i & 63;
    wt[d * CSZ + c] = cb[i];
  }
  if (t < CSZ) {
    float a = 0.0f;
    for (int d = 0; d < DDIM; ++d) { const float v = cb[t * DDIM + d]; a += v * v; }
    wsq[t] = a;
  }
}

// ---- main: per block of 16 rows: s = wsq - 2 z.Wt (fp32 VALU GEMM), then
//      argmin (top-2 + fp64 tiebreak), online softmax over the LDS s-tile,
//      prob partials, dist accumulation, z_q gather + index write ----
__global__ __launch_bounds__(256) void vq_main(const float* __restrict__ z,
                                               const float* __restrict__ cb,
                                               const float* __restrict__ wt,
                                               const float* __restrict__ wsq,
                                               float* __restrict__ probpart,
                                               float* __restrict__ distsum,
                                               float* __restrict__ out_zq,
                                               float* __restrict__ out_idx) {
  __shared__ float s[TR * CSZ];   // 64 KB exactly
  const int tid = threadIdx.x;
  const int r0  = blockIdx.x * TR;
  const int c4  = tid * 4;        // this thread's 4 codes (covers all 1024 across block)

  // ---------------- GEMM phase: acc[r][j] = dot(z_row r, w_code c4+j) ----------------
  float acc[TR][4];
  #pragma unroll
  for (int r = 0; r < TR; ++r) { acc[r][0] = acc[r][1] = acc[r][2] = acc[r][3] = 0.0f; }

  for (int d = 0; d < DDIM; d += 4) {
    const float4 w0 = *(const float4*)(wt + (size_t)(d + 0) * CSZ + c4);
    const float4 w1 = *(const float4*)(wt + (size_t)(d + 1) * CSZ + c4);
    const float4 w2 = *(const float4*)(wt + (size_t)(d + 2) * CSZ + c4);
    const float4 w3 = *(const float4*)(wt + (size_t)(d + 3) * CSZ + c4);
    #pragma unroll
    for (int r = 0; r < TR; ++r) {
      const float4 zv = *(const float4*)(z + (size_t)(r0 + r) * DDIM + d);  // block-uniform
      acc[r][0] += zv.x * w0.x + zv.y * w1.x + zv.z * w2.x + zv.w * w3.x;
      acc[r][1] += zv.x * w0.y + zv.y * w1.y + zv.z * w2.y + zv.w * w3.y;
      acc[r][2] += zv.x * w0.z + zv.y * w1.z + zv.z * w2.z + zv.w * w3.z;
      acc[r][3] += zv.x * w0.w + zv.y * w1.w + zv.z * w2.w + zv.w * w3.w;
    }
  }
  {
    const float4 wq = *(const float4*)(wsq + c4);
    #pragma unroll
    for (int r = 0; r < TR; ++r) {
      float4 sv;
      sv.x = wq.x - 2.0f * acc[r][0];
      sv.y = wq.y - 2.0f * acc[r][1];
      sv.z = wq.z - 2.0f * acc[r][2];
      sv.w = wq.w - 2.0f * acc[r][3];
      *(float4*)(&s[r * CSZ + c4]) = sv;
    }
  }
  __syncthreads();

  // ---------------- per-row reductions: wave w handles rows 4w..4w+3 ----------------
  const int wave = tid >> 6, lane = tid & 63;
  float dacc = 0.0f;
  for (int k4 = 0; k4 < 4; ++k4) {
    const int r = wave * 4 + k4;
    const int n = r0 + r;

    // top-2 (value, index) with first-index tie-break (matches jnp.argmin)
    float m1 = 3.4e38f, m2 = 3.4e38f; int i1 = CSZ, i2 = CSZ;
    #pragma unroll
    for (int k = 0; k < 16; ++k) {
      const int c = lane + 64 * k;
      top2_insert(s[r * CSZ + c], c, m1, i1, m2, i2);
    }
    #pragma unroll
    for (int off = 1; off < 64; off <<= 1) {
      const float pm1 = __shfl_xor(m1, off); const int pi1 = __shfl_xor(i1, off);
      const float pm2 = __shfl_xor(m2, off); const int pi2 = __shfl_xor(i2, off);
      top2_insert(pm1, pi1, m1, i1, m2, i2);
      top2_insert(pm2, pi2, m1, i1, m2, i2);
    }

    // softmax over -s (shift-invariant: identical to softmax over -dist)
    const float m = m1;
    float e[16]; float esum = 0.0f;
    #pragma unroll
    for (int k = 0; k < 16; ++k) {
      e[k] = __expf(m - s[r * CSZ + lane + 64 * k]);
      esum += e[k];
    }
    const float zz = z[(size_t)n * DDIM + lane];
    float zsq = zz * zz;
    #pragma unroll
    for (int off = 1; off < 64; off <<= 1) {
      esum += __shfl_xor(esum, off);
      zsq  += __shfl_xor(zsq, off);
    }
    const float invl = 1.0f / esum;
    #pragma unroll
    for (int k = 0; k < 16; ++k) s[r * CSZ + lane + 64 * k] = e[k] * invl;

    // fp64 refinement of argmin when the top-2 gap is within fp32 noise margin
    int idx = i1; float dmin = m1;
    if (m2 - m1 < 1e-2f) {
      const float* zr = z  + (size_t)n  * DDIM;
      const float* wa = cb + (size_t)i1 * DDIM;
      const float* wb = cb + (size_t)i2 * DDIM;
      double da = 0.0, db = 0.0;
      for (int d = 0; d < DDIM; ++d) {
        const double t1 = (double)zr[d] - (double)wa[d]; da += t1 * t1;
        const double t2 = (double)zr[d] - (double)wb[d]; db += t2 * t2;
      }
      if (db < da || (db == da && i2 < i1)) { idx = i2; dmin = m2; }
    }
    if (lane == 0) {
      out_idx[n] = (float)idx;
      dacc += dmin + zsq;       // ||z-w*||^2 = s_min + ||z||^2
    }
    // z_q gather (idx is uniform across the wave after the butterfly)
    out_zq[(size_t)n * DDIM + lane] = cb[(size_t)idx * DDIM + lane];
  }
  if (lane == 0) atomicAdd(distsum, dacc);
  __syncthreads();

  // prob partial accumulation: s now holds normalized p; column-sum the 16 rows
  float* pp = probpart + (size_t)(blockIdx.x & (NSLOT - 1)) * CSZ;
  #pragma unroll
  for (int k = 0; k < 4; ++k) {
    const int c = tid + 256 * k;       // stride-1 across lanes: conflict-free LDS
    float a = 0.0f;
    #pragma unroll
    for (int r = 0; r < TR; ++r) a += s[r * CSZ + c];
    atomicAdd(&pp[c], a);
  }
}

// ---- finalize: entropy of avg probs + assemble total loss ----
__global__ __launch_bounds__(256) void vq_finalize(const float* __restrict__ probpart,
                                                   const float* __restrict__ distsum,
                                                   float* __restrict__ out_loss) {
  __shared__ float red[256];
  const int t = threadIdx.x;
  float ent = 0.0f;
  for (int c = t; c < CSZ; c += 256) {
    float p = 0.0f;
    for (int k = 0; k < NSLOT; ++k) p += probpart[k * CSZ + c];
    p *= (1.0f / (float)NROWS);
    ent -= p * logf(p + 1e-10f);
  }
  red[t] = ent;
  __syncthreads();
  for (int sft = 128; sft > 0; sft >>= 1) {
    if (t < sft) red[t] += red[t + sft];
    __syncthreads();
  }
  if (t == 0) {
    const float maxH  = logf(1024.0f);
    const float eloss = 0.1f * (maxH - red[0]) / maxH;
    const float mse   = distsum[0] / ((float)NROWS * (float)DDIM);
    out_loss[0] = 1.25f * mse + eloss;   // commit(0.25) + codebook(1.0) + entropy
  }
}

extern "C" void kernel_launch(void* const* d_in, const int* in_sizes, int n_in,
                              void* d_out, int out_size, void* d_ws, size_t ws_size,
                              hipStream_t stream) {
  const float* z  = (const float*)d_in[0];   // [32,4096,64]
  const float* cb = (const float*)d_in[1];   // [1024,64]
  float* ws       = (float*)d_ws;
  float* wt       = ws;                       // 65536
  float* wsq      = ws + 65536;               // 1024
  float* probpart = ws + 66560;               // 65536
  float* distsum  = ws + 132096;              // 1

  float* out      = (float*)d_out;
  float* out_zq   = out;                      // 8388608
  float* out_loss = out + 8388608;            // 1
  float* out_idx  = out + 8388609;            // 131072

  vq_prep<<<64, 256, 0, stream>>>(cb, wt, wsq, probpart, distsum);
  vq_main<<<NROWS / TR, 256, 0, stream>>>(z, cb, wt, wsq, probpart, distsum, out_zq, out_idx);
  vq_finalize<<<1, 256, 0, stream>>>(probpart, distsum, out_loss);
}